// Round 3
// baseline (29.040 us; speedup 1.0000x reference)
//
#include <hip/hip_runtime.h>

#define NN 1024
#define DD 64
#define NF 11
#define TI 4

// Softmax-without-max is exact here: valid scores are in (-1, 0] and masked
// scores are -1e9 -> __expf underflows to +0.0. len >= 1 guarantees every
// row-sum > 0 (no NaN path).
__global__ __launch_bounds__(256, 4) void featuresim_kernel(
    const float* __restrict__ x,
    const int* __restrict__ x_lengths,
    const float* __restrict__ fimp,
    float* __restrict__ out)
{
    const int tid = threadIdx.x;
    const int b   = blockIdx.x >> 8;            // 256 row-groups per batch
    const int i0  = (blockIdx.x & 255) * TI;
    const int len = x_lengths[b];

    // feature_importance: uniform address -> s_load -> SGPRs
    float fi[NF];
    #pragma unroll
    for (int k = 0; k < NF; ++k) fi[k] = fimp[k];

    // each thread owns 4 consecutive j's; their 11 features live in VGPRs
    const int j0 = tid * 4;
    float fj[4][NF];
    #pragma unroll
    for (int jj = 0; jj < 4; ++jj) {
        const float4* p = reinterpret_cast<const float4*>(
            x + (size_t)(b * NN + j0 + jj) * DD);
        float4 a = p[0], c = p[1], d = p[2];
        fj[jj][0] = a.x; fj[jj][1] = a.y; fj[jj][2]  = a.z; fj[jj][3] = a.w;
        fj[jj][4] = c.x; fj[jj][5] = c.y; fj[jj][6]  = c.z; fj[jj][7] = c.w;
        fj[jj][8] = d.x; fj[jj][9] = d.y; fj[jj][10] = d.z;
    }

    // hoisted key-validity masks (loop-invariant across rows)
    bool valid[4];
    #pragma unroll
    for (int jj = 0; jj < 4; ++jj) valid[jj] = (j0 + jj) < len;

    __shared__ float partials[TI][256];   // [row][thread] — conflict-free both phases
    __shared__ float totals[TI];

    float e[TI][4];                       // statically indexed -> VGPRs (~16 regs)

    // ---- phase 1: all TI rows' exp values + per-thread partial sums, no barriers
    #pragma unroll
    for (int r = 0; r < TI; ++r) {
        const float* qp = x + (size_t)(b * NN + i0 + r) * DD;  // uniform -> s_load
        float q[NF];
        #pragma unroll
        for (int k = 0; k < NF; ++k) q[k] = qp[k];

        float sum4 = 0.0f;
        #pragma unroll
        for (int jj = 0; jj < 4; ++jj) {
            float s = 0.0f;                      // accumulates -attn directly
            #pragma unroll
            for (int k = 0; k < NF; ++k) {
                float d = q[k] - fj[jj][k];
                s = fmaf(-fabsf(d), fi[k], s);   // -abs() folds to VOP3 input mod
            }
            float val = (s > -1.0f) ? s : 0.0f;  // (attn<1) ? -attn : 0
            float ev  = valid[jj] ? __expf(val) : 0.0f;
            e[r][jj] = ev;
            sum4 += ev;
        }
        partials[r][tid] = sum4;
    }
    __syncthreads();

    // ---- phase 2: wave w reduces row w (TI==4 waves, one row each)
    const int lane = tid & 63;
    const int wid  = tid >> 6;
    {
        const int r = wid;
        float s = partials[r][lane]       + partials[r][lane + 64]
                + partials[r][lane + 128] + partials[r][lane + 192];
        #pragma unroll
        for (int off = 32; off >= 1; off >>= 1)
            s += __shfl_xor(s, off, 64);
        if (lane == 0) totals[r] = s;
    }
    __syncthreads();

    // ---- phase 3: normalize + coalesced float4 stores
    #pragma unroll
    for (int r = 0; r < TI; ++r) {
        const float inv = __builtin_amdgcn_rcpf(totals[r]);
        float4 o = make_float4(e[r][0] * inv, e[r][1] * inv,
                               e[r][2] * inv, e[r][3] * inv);
        reinterpret_cast<float4*>(
            out + (size_t)(b * NN + i0 + r) * NN + j0)[0] = o;
    }
}

extern "C" void kernel_launch(void* const* d_in, const int* in_sizes, int n_in,
                              void* d_out, int out_size, void* d_ws, size_t ws_size,
                              hipStream_t stream) {
    const float* x    = (const float*)d_in[0];
    const int*   xlen = (const int*)d_in[1];
    const float* fimp = (const float*)d_in[2];
    float*       out  = (float*)d_out;

    const int B = in_sizes[1];                  // 8
    dim3 grid(B * (NN / TI));                   // 2048 blocks
    dim3 block(256);
    featuresim_kernel<<<grid, block, 0, stream>>>(x, xlen, fimp, out);
}

// Round 4
// 21.673 us; speedup vs baseline: 1.3399x; 1.3399x over previous
//
#include <hip/hip_runtime.h>

#define NN 1024
#define DD 64
#define NF 11
#define TI 8
#define JT 2          // j's per thread
#define BT 512        // threads per block

// Softmax-without-max is exact here: valid scores are in (-1, 0] and masked
// scores -> exp underflow to +0.0. len >= 1 guarantees row-sum > 0.
__global__ __launch_bounds__(BT, 8) void featuresim_kernel(
    const float* __restrict__ x,
    const int* __restrict__ x_lengths,
    const float* __restrict__ fimp,
    float* __restrict__ out)
{
    const int tid = threadIdx.x;
    const int b   = blockIdx.x >> 7;            // 128 row-groups per batch
    const int i0  = (blockIdx.x & 127) * TI;
    const int len = x_lengths[b];

    // feature_importance: uniform -> SGPRs
    float fi[NF];
    #pragma unroll
    for (int k = 0; k < NF; ++k) fi[k] = fimp[k];

    // each thread owns 2 consecutive j's; 22 VGPRs of key features
    const int j0 = tid * JT;
    float fj[JT][NF];
    #pragma unroll
    for (int jj = 0; jj < JT; ++jj) {
        const float4* p = reinterpret_cast<const float4*>(
            x + (size_t)(b * NN + j0 + jj) * DD);
        float4 a = p[0], c = p[1], d = p[2];
        fj[jj][0] = a.x; fj[jj][1] = a.y; fj[jj][2]  = a.z; fj[jj][3] = a.w;
        fj[jj][4] = c.x; fj[jj][5] = c.y; fj[jj][6]  = c.z; fj[jj][7] = c.w;
        fj[jj][8] = d.x; fj[jj][9] = d.y; fj[jj][10] = d.z;
    }

    bool valid[JT];
    #pragma unroll
    for (int jj = 0; jj < JT; ++jj) valid[jj] = (j0 + jj) < len;

    __shared__ float partials[TI][BT];    // 16 KiB
    __shared__ float totals[TI];

    float e[TI][JT];                      // 16 VGPRs

    // ---- phase 1: all rows' exp values + per-thread partials, no barriers
    #pragma unroll
    for (int r = 0; r < TI; ++r) {
        const float* qp = x + (size_t)(b * NN + i0 + r) * DD;  // uniform -> s_load
        float q[NF];
        #pragma unroll
        for (int k = 0; k < NF; ++k) q[k] = qp[k];

        float psum = 0.0f;
        #pragma unroll
        for (int jj = 0; jj < JT; ++jj) {
            float s = 0.0f;                       // accumulates -attn
            #pragma unroll
            for (int k = 0; k < NF; ++k) {
                float d = q[k] - fj[jj][k];
                s = fmaf(-fabsf(d), fi[k], s);    // -abs() is a VOP3 input mod
            }
            float val = (s > -1.0f) ? s : 0.0f;
            float ev  = valid[jj] ? __expf(val) : 0.0f;
            e[r][jj] = ev;
            psum += ev;
        }
        partials[r][tid] = psum;
    }
    __syncthreads();

    // ---- phase 2: wave w reduces row w (8 waves, one row each)
    const int lane = tid & 63;
    const int wid  = tid >> 6;
    {
        float s = 0.0f;
        #pragma unroll
        for (int m = 0; m < BT / 64; ++m)
            s += partials[wid][lane + 64 * m];
        #pragma unroll
        for (int off = 32; off >= 1; off >>= 1)
            s += __shfl_xor(s, off, 64);
        if (lane == 0) totals[wid] = s;
    }
    __syncthreads();

    // ---- phase 3: normalize + coalesced float2 stores
    #pragma unroll
    for (int r = 0; r < TI; ++r) {
        const float inv = __builtin_amdgcn_rcpf(totals[r]);
        float2 o = make_float2(e[r][0] * inv, e[r][1] * inv);
        reinterpret_cast<float2*>(
            out + (size_t)(b * NN + i0 + r) * NN + j0)[0] = o;
    }
}

extern "C" void kernel_launch(void* const* d_in, const int* in_sizes, int n_in,
                              void* d_out, int out_size, void* d_ws, size_t ws_size,
                              hipStream_t stream) {
    const float* x    = (const float*)d_in[0];
    const int*   xlen = (const int*)d_in[1];
    const float* fimp = (const float*)d_in[2];
    float*       out  = (float*)d_out;

    const int B = in_sizes[1];                  // 8
    dim3 grid(B * (NN / TI));                   // 1024 blocks
    dim3 block(BT);
    featuresim_kernel<<<grid, block, 0, stream>>>(x, xlen, fimp, out);
}

// Round 5
// 19.207 us; speedup vs baseline: 1.5120x; 1.1284x over previous
//
#include <hip/hip_runtime.h>

#define NN 1024
#define DD 64
#define NF 11
#define TI 16
#define BT 1024

// Softmax-without-max is exact here: valid scores are in (-1, 0] and masked
// keys contribute exactly 0. len >= 1 guarantees every row-sum > 0.
// VGPR budget: fj[11] + e[16] + ~12 temps ≈ 40 < 64 cap -> no spill at
// 8 waves/EU (32 waves/CU, 100% occupancy, 2x1024-thr blocks/CU).
__global__ __launch_bounds__(BT, 8) void featuresim_kernel(
    const float* __restrict__ x,
    const int* __restrict__ x_lengths,
    const float* __restrict__ fimp,
    float* __restrict__ out)
{
    const int tid = threadIdx.x;
    const int b   = blockIdx.x >> 6;            // 64 row-groups per batch
    const int i0  = (blockIdx.x & 63) * TI;
    const int len = x_lengths[b];

    // feature_importance: uniform -> SGPRs
    float fi[NF];
    #pragma unroll
    for (int k = 0; k < NF; ++k) fi[k] = fimp[k];

    // each thread owns ONE key row j = tid; 11 VGPRs of key features
    const int j0 = tid;
    float fj[NF];
    {
        const float4* p = reinterpret_cast<const float4*>(
            x + (size_t)(b * NN + j0) * DD);
        float4 a = p[0], c = p[1], d = p[2];
        fj[0] = a.x; fj[1] = a.y; fj[2]  = a.z; fj[3] = a.w;
        fj[4] = c.x; fj[5] = c.y; fj[6]  = c.z; fj[7] = c.w;
        fj[8] = d.x; fj[9] = d.y; fj[10] = d.z;
    }
    const bool valid = j0 < len;

    __shared__ float partials[TI][BT];    // 64 KiB; conflict-free both phases
    __shared__ float totals[TI];

    float e[TI];                          // statically indexed -> 16 VGPRs

    // ---- phase 1: all 16 rows' exp values, no barriers
    #pragma unroll
    for (int r = 0; r < TI; ++r) {
        const float* qp = x + (size_t)(b * NN + i0 + r) * DD;  // uniform -> s_load
        float q[NF];
        #pragma unroll
        for (int k = 0; k < NF; ++k) q[k] = qp[k];

        float s = 0.0f;                        // accumulates -attn
        #pragma unroll
        for (int k = 0; k < NF; ++k) {
            float d = q[k] - fj[k];
            s = fmaf(-fabsf(d), fi[k], s);     // -abs() is a VOP3 input mod
        }
        float val = (s > -1.0f) ? s : 0.0f;    // (attn<1) ? -attn : 0
        float ev  = valid ? __expf(val) : 0.0f;
        e[r] = ev;
        partials[r][tid] = ev;
    }
    __syncthreads();

    // ---- phase 2: wave w reduces row w (16 waves, one row each)
    const int lane = tid & 63;
    const int wid  = tid >> 6;
    {
        float s = 0.0f;
        #pragma unroll
        for (int m = 0; m < BT / 64; ++m)
            s += partials[wid][lane + 64 * m];
        #pragma unroll
        for (int off = 32; off >= 1; off >>= 1)
            s += __shfl_xor(s, off, 64);
        if (lane == 0) totals[wid] = s;
    }
    __syncthreads();

    // ---- phase 3: normalize + coalesced dword stores (256B/wave)
    #pragma unroll
    for (int r = 0; r < TI; ++r) {
        const float inv = __builtin_amdgcn_rcpf(totals[r]);
        out[(size_t)(b * NN + i0 + r) * NN + j0] = e[r] * inv;
    }
}

extern "C" void kernel_launch(void* const* d_in, const int* in_sizes, int n_in,
                              void* d_out, int out_size, void* d_ws, size_t ws_size,
                              hipStream_t stream) {
    const float* x    = (const float*)d_in[0];
    const int*   xlen = (const int*)d_in[1];
    const float* fimp = (const float*)d_in[2];
    float*       out  = (float*)d_out;

    const int B = in_sizes[1];                  // 8
    dim3 grid(B * (NN / TI));                   // 512 blocks = 1 resident generation
    dim3 block(BT);
    featuresim_kernel<<<grid, block, 0, stream>>>(x, xlen, fimp, out);
}